// Round 8
// baseline (299.115 us; speedup 1.0000x reference)
//
#include <hip/hip_runtime.h>
#include <stdint.h>

// EETQLinear w8a16: out[m,n] = (sum_k x[m,k]*wq[k,n]) * scale[n] + bias[n]
// M=8192, K=4096, N=4096. Dtypes (r3/r4-verified): x/scale/bias/out f32, wq int32.
// v8: r7's min-barrier schedule, MFMA shape 16x16x32 -> 32x32x16 (2x FLOP/instr,
//     higher ceiling 2382+ vs 2075 TF). acc[4][2] f32x16; frag row=l&31,
//     k=(l>>5)*8+j; C/D col=lane&31, row=(reg&3)+8*(reg>>2)+4*(lane>>5) [m74/m101].

typedef __attribute__((ext_vector_type(16))) float    f32x16;
typedef __attribute__((ext_vector_type(8))) _Float16  f16x8;

#define M_DIM 8192
#define N_DIM 4096
#define K_DIM 4096

// ---------------- prologue kernels (r4-verified) ----------------
__global__ __launch_bounds__(256) void convert_x_to_f16(const float* __restrict__ x,
                                                        _Float16* __restrict__ Xh) {
    const size_t i = ((size_t)blockIdx.x * 256 + threadIdx.x) * 8;
    float4 v0 = *(const float4*)(x + i);
    float4 v1 = *(const float4*)(x + i + 4);
    f16x8 h;
    h[0] = (_Float16)v0.x; h[1] = (_Float16)v0.y; h[2] = (_Float16)v0.z; h[3] = (_Float16)v0.w;
    h[4] = (_Float16)v1.x; h[5] = (_Float16)v1.y; h[6] = (_Float16)v1.z; h[7] = (_Float16)v1.w;
    *(f16x8*)(Xh + i) = h;
}

__global__ __launch_bounds__(256) void dequant_w_to_f16(const int* __restrict__ wq,
                                                        _Float16* __restrict__ Wt) {
    __shared__ _Float16 tile[64][65];
    const int n0 = blockIdx.x * 64;
    const int k0 = blockIdx.y * 64;
    const int t  = threadIdx.x;
    const int r  = t >> 2;
    const int c0 = (t & 3) * 16;
    const int* src = wq + (size_t)(k0 + r) * N_DIM + n0 + c0;
#pragma unroll
    for (int j = 0; j < 4; ++j) {
        int4 q = *(const int4*)(src + j * 4);
        tile[c0 + j * 4 + 0][r] = (_Float16)q.x;
        tile[c0 + j * 4 + 1][r] = (_Float16)q.y;
        tile[c0 + j * 4 + 2][r] = (_Float16)q.z;
        tile[c0 + j * 4 + 3][r] = (_Float16)q.w;
    }
    __syncthreads();
    const int nn  = t >> 2;
    const int cc0 = (t & 3) * 16;
    _Float16 vals[16] __attribute__((aligned(16)));
#pragma unroll
    for (int j = 0; j < 16; ++j) vals[j] = tile[nn][cc0 + j];
    _Float16* dst = Wt + (size_t)(n0 + nn) * K_DIM + k0 + cc0;
    *(float4*)(dst + 0) = *(const float4*)(vals + 0);
    *(float4*)(dst + 8) = *(const float4*)(vals + 8);
}

// ---------------- min-barrier 256x256 GEMM, 32x32x16 MFMA ----------------
#define AS1C(p) (const __attribute__((address_space(1))) void*)(p)
#define AS3C(p) (__attribute__((address_space(3))) void*)(p)

#define STAGE_A(arr, h, tile) do {                                                    \
    __builtin_amdgcn_global_load_lds(                                                 \
        AS1C(aStageBase + (size_t)((h) * 128) * K_DIM + (tile) * 64),                 \
        AS3C((char*)(arr) + (h) * 16384 + t * 16), 16, 0, 0);                         \
    __builtin_amdgcn_global_load_lds(                                                 \
        AS1C(aStageBase + (size_t)((h) * 128 + 64) * K_DIM + (tile) * 64),            \
        AS3C((char*)(arr) + (h) * 16384 + 8192 + t * 16), 16, 0, 0);                  \
} while (0)

#define STAGE_B(arr, h, tile) do {                                                    \
    __builtin_amdgcn_global_load_lds(                                                 \
        AS1C(bStageBase + (size_t)((h) * 128) * K_DIM + (tile) * 64),                 \
        AS3C((char*)(arr) + (h) * 16384 + t * 16), 16, 0, 0);                         \
    __builtin_amdgcn_global_load_lds(                                                 \
        AS1C(bStageBase + (size_t)((h) * 128 + 64) * K_DIM + (tile) * 64),            \
        AS3C((char*)(arr) + (h) * 16384 + 8192 + t * 16), 16, 0, 0);                  \
} while (0)

#define DSR(dst, addr, IMM) \
    asm volatile("ds_read_b128 %0, %1 offset:%c2" : "=v"(dst) : "v"(addr), "i"(IMM))

// one k-step's fragments into reg set S: 4 A-quads (+am*32 rows = +4096B) + 2 B-quads
#define DSRK(S, aA, bA)                      \
    DSR(afr##S[0], aA, 0);                   \
    DSR(afr##S[1], aA, 4096);                \
    DSR(afr##S[2], aA, 8192);                \
    DSR(afr##S[3], aA, 12288);               \
    DSR(bfr##S[0], bA, 0);                   \
    DSR(bfr##S[1], bA, 4096)

#define MM32(S, AI, BI)                                                               \
    acc[AI][BI] = __builtin_amdgcn_mfma_f32_32x32x16_f16(afr##S[AI], bfr##S[BI],      \
                                                         acc[AI][BI], 0, 0, 0)

#define MFMA8(S)                                                      \
    MM32(S, 0, 0); MM32(S, 0, 1); MM32(S, 1, 0); MM32(S, 1, 1);       \
    MM32(S, 2, 0); MM32(S, 2, 1); MM32(S, 3, 0); MM32(S, 3, 1)

#define BARR()  __builtin_amdgcn_s_barrier()
#define SB0()   __builtin_amdgcn_sched_barrier(0)
#define LGKM0() do { asm volatile("s_waitcnt lgkmcnt(0)" ::: "memory"); SB0(); } while (0)
#define LGKM6() do { asm volatile("s_waitcnt lgkmcnt(6)" ::: "memory"); SB0(); } while (0)
#define VMC2()  asm volatile("s_waitcnt vmcnt(2)" ::: "memory")
#define PRIO1() __builtin_amdgcn_s_setprio(1)
#define PRIO0() __builtin_amdgcn_s_setprio(0)

// One K-tile (BK=64, 4 k-steps of K=16). 2 barriers. lgkm ledger:
//   issue 12 -> w6 (set0 ok) -> issue 6 -> w6 (set1 ok) -> issue 6 -> w6 (set0 ok)
//   -> w0 (set1 ok). vmcnt ledger: 8/tile, VMC2 with next tile's 2 in flight.
#define KTILE(aAd, bAd, Adst, Bdst, tl) do {                                          \
    STAGE_A(Adst, 0, tl);                   /* dst pair freed by prev end-BARR */     \
    VMC2();                                 /* my 8 loads of THIS tile landed */      \
    BARR();                                 /* ... and everyone else's */             \
    DSRK(0, aAd[0], bAd[0]);                                                          \
    DSRK(1, aAd[1], bAd[1]);                                                          \
    LGKM6();  PRIO1(); MFMA8(0); PRIO0();                                             \
    DSRK(0, aAd[2], bAd[2]);  STAGE_A(Adst, 1, tl);                                   \
    LGKM6();  PRIO1(); MFMA8(1); PRIO0();                                             \
    DSRK(1, aAd[3], bAd[3]);  STAGE_B(Bdst, 0, tl);                                   \
    LGKM6();  PRIO1(); MFMA8(0); PRIO0();                                             \
    STAGE_B(Bdst, 1, tl);                                                             \
    LGKM0();  PRIO1(); MFMA8(1); PRIO0();                                             \
    BARR();                                 /* all waves done reading this pair */    \
} while (0)

__global__ __launch_bounds__(512, 2) void gemm_mb32(const _Float16* __restrict__ Xh,
                                                    const _Float16* __restrict__ Wt,
                                                    const float* __restrict__ scale,
                                                    const float* __restrict__ bias,
                                                    float* __restrict__ C) {
    __shared__ __attribute__((aligned(128))) _Float16 As0_[16384];  // [256][64] f16
    __shared__ __attribute__((aligned(128))) _Float16 As1_[16384];
    __shared__ __attribute__((aligned(128))) _Float16 Bs0_[16384];
    __shared__ __attribute__((aligned(128))) _Float16 Bs1_[16384];

    // T1: XCD-aware bijective swizzle (512 blocks, 512 % 8 == 0)
    const int bid = blockIdx.x;
    const int swz = (bid & 7) * 64 + (bid >> 3);
    const int bm  = swz >> 4;            // 0..31
    const int bn  = swz & 15;            // 0..15

    const int t  = threadIdx.x;          // 0..511
    const int l  = t & 63;
    const int w  = t >> 6;               // 8 waves: 2(M) x 4(N)
    const int wm = w >> 2, wn = w & 3;   // wave block: 128 rows x 64 cols

    // staging (unchanged, r5-verified): rows (t>>3)+{0,64} per half, k-slot t&7,
    // source k pre-XORed by ((row&7)<<4) bytes; LDS dest linear.
    const int rowIdx = t >> 3;
    const int kbSw   = ((t & 7) * 16) ^ ((rowIdx & 7) << 4);
    const _Float16* aStageBase = Xh + (size_t)(bm * 256 + rowIdx) * K_DIM + (kbSw >> 1);
    const _Float16* bStageBase = Wt + (size_t)(bn * 256 + rowIdx) * K_DIM + (kbSw >> 1);

    // 32x32 fragment read addresses: row = (l&31) (+quad via imm), k-byte for
    // k-step κ = (κ*32 + (l>>5)*16) ^ ((l&7)<<4)  [same involution as staging]
    const int col32 = l & 31;
    const int kh16  = (l >> 5) * 16;
    const int mask7 = (l & 7) << 4;
    const uint32_t aRowOff = (uint32_t)((wm * 128 + col32) * 128);
    const uint32_t bRowOff = (uint32_t)((wn * 64 + col32) * 128);
    uint32_t aAd0[4], aAd1[4], bAd0[4], bAd1[4];
#pragma unroll
    for (int ks = 0; ks < 4; ++ks) {
        const uint32_t bk = (uint32_t)((ks * 32 + kh16) ^ mask7);
        aAd0[ks] = (uint32_t)(uintptr_t)As0_ + aRowOff + bk;
        aAd1[ks] = (uint32_t)(uintptr_t)As1_ + aRowOff + bk;
        bAd0[ks] = (uint32_t)(uintptr_t)Bs0_ + bRowOff + bk;
        bAd1[ks] = (uint32_t)(uintptr_t)Bs1_ + bRowOff + bk;
    }

    f16x8 afr0[4], afr1[4], bfr0[2], bfr1[2];
    f32x16 acc[4][2] = {};

    // prologue: stage K-tile 0 into buf0 (8 loads/wave outstanding)
    STAGE_A(As0_, 0, 0); STAGE_A(As0_, 1, 0);
    STAGE_B(Bs0_, 0, 0); STAGE_B(Bs0_, 1, 0);

#pragma unroll 1
    for (int i = 0; i < K_DIM / 128; ++i) {       // 32 iters, 2 K-tiles each
        const int t1 = 2 * i + 1;                 // <= 63
        const int t2 = (2 * i + 2) & 63;          // wraps only on last iter (data unused)
        KTILE(aAd0, bAd0, As1_, Bs1_, t1);        // tile 2i   (buf0)
        KTILE(aAd1, bAd1, As0_, Bs0_, t2);        // tile 2i+1 (buf1)
    }
    asm volatile("s_waitcnt vmcnt(0)" ::: "memory");  // drain dangling prefetch

    // epilogue: C/D col = lane&31, row = (reg&3) + 8*(reg>>2) + 4*(lane>>5)
    const int colBase = bn * 256 + wn * 64 + col32;          // + b2*32
    const int rowBase = bm * 256 + wm * 128 + 4 * (l >> 5);  // + am*32 + (reg&3) + 8*(reg>>2)
    float sc[2], bi[2];
#pragma unroll
    for (int b2 = 0; b2 < 2; ++b2) {
        sc[b2] = scale[colBase + b2 * 32];
        bi[b2] = bias[colBase + b2 * 32];
    }
#pragma unroll
    for (int am = 0; am < 4; ++am)
#pragma unroll
        for (int b2 = 0; b2 < 2; ++b2)
#pragma unroll
            for (int reg = 0; reg < 16; ++reg) {
                const int row = rowBase + am * 32 + (reg & 3) + 8 * (reg >> 2);
                C[(size_t)row * N_DIM + colBase + b2 * 32] =
                    acc[am][b2][reg] * sc[b2] + bi[b2];
            }
}

extern "C" void kernel_launch(void* const* d_in, const int* in_sizes, int n_in,
                              void* d_out, int out_size, void* d_ws, size_t ws_size,
                              hipStream_t stream) {
    const float* x     = (const float*)d_in[0];
    const int*   wq    = (const int*)d_in[1];
    const float* scale = (const float*)d_in[2];
    const float* bias  = (const float*)d_in[3];
    float* out = (float*)d_out;

    const size_t needW = (size_t)N_DIM * K_DIM * sizeof(_Float16);   // 33.5 MB
    _Float16* Wt = (_Float16*)d_ws;
    _Float16* Xh = (_Float16*)((char*)d_ws + needW);                 // ws >= 100.7MB (r4)

    dim3 tgrid(N_DIM / 64, K_DIM / 64);
    dequant_w_to_f16<<<tgrid, 256, 0, stream>>>(wq, Wt);
    convert_x_to_f16<<<((size_t)M_DIM * K_DIM) / (256 * 8), 256, 0, stream>>>(x, Xh);

    const int nblocks = (M_DIM / 256) * (N_DIM / 256);               // 512
    gemm_mb32<<<nblocks, 512, 0, stream>>>(Xh, Wt, scale, bias, out);
}

// Round 9
// 290.856 us; speedup vs baseline: 1.0284x; 1.0284x over previous
//
#include <hip/hip_runtime.h>
#include <stdint.h>

// EETQLinear w8a16: out[m,n] = (sum_k x[m,k]*wq[k,n]) * scale[n] + bias[n]
// M=8192, K=4096, N=4096. Dtypes (r3/r4-verified): x/scale/bias/out f32, wq int32.
// v9: OCCUPANCY round. 256x256 tile, 16 waves (4Mx4N, 64x64 out each), <=128
//     regs/wave (__launch_bounds__(1024,4)) -> 4 waves/SIMD (2x r7). Simple
//     2-barrier K-tile with counted vmcnt(4); TLP hides ds_read/DMA latency.
//     Keeps r5/r7's verified conflict-free swizzle + 16x16x32 f16 MFMA.

typedef __attribute__((ext_vector_type(4))) float     f32x4;
typedef __attribute__((ext_vector_type(8))) _Float16  f16x8;

#define M_DIM 8192
#define N_DIM 4096
#define K_DIM 4096

// ---------------- prologue kernels (r4-verified) ----------------
__global__ __launch_bounds__(256) void convert_x_to_f16(const float* __restrict__ x,
                                                        _Float16* __restrict__ Xh) {
    const size_t i = ((size_t)blockIdx.x * 256 + threadIdx.x) * 8;
    float4 v0 = *(const float4*)(x + i);
    float4 v1 = *(const float4*)(x + i + 4);
    f16x8 h;
    h[0] = (_Float16)v0.x; h[1] = (_Float16)v0.y; h[2] = (_Float16)v0.z; h[3] = (_Float16)v0.w;
    h[4] = (_Float16)v1.x; h[5] = (_Float16)v1.y; h[6] = (_Float16)v1.z; h[7] = (_Float16)v1.w;
    *(f16x8*)(Xh + i) = h;
}

__global__ __launch_bounds__(256) void dequant_w_to_f16(const int* __restrict__ wq,
                                                        _Float16* __restrict__ Wt) {
    __shared__ _Float16 tile[64][65];
    const int n0 = blockIdx.x * 64;
    const int k0 = blockIdx.y * 64;
    const int t  = threadIdx.x;
    const int r  = t >> 2;
    const int c0 = (t & 3) * 16;
    const int* src = wq + (size_t)(k0 + r) * N_DIM + n0 + c0;
#pragma unroll
    for (int j = 0; j < 4; ++j) {
        int4 q = *(const int4*)(src + j * 4);
        tile[c0 + j * 4 + 0][r] = (_Float16)q.x;
        tile[c0 + j * 4 + 1][r] = (_Float16)q.y;
        tile[c0 + j * 4 + 2][r] = (_Float16)q.z;
        tile[c0 + j * 4 + 3][r] = (_Float16)q.w;
    }
    __syncthreads();
    const int nn  = t >> 2;
    const int cc0 = (t & 3) * 16;
    _Float16 vals[16] __attribute__((aligned(16)));
#pragma unroll
    for (int j = 0; j < 16; ++j) vals[j] = tile[nn][cc0 + j];
    _Float16* dst = Wt + (size_t)(n0 + nn) * K_DIM + k0 + cc0;
    *(float4*)(dst + 0) = *(const float4*)(vals + 0);
    *(float4*)(dst + 8) = *(const float4*)(vals + 8);
}

// ---------------- 16-wave 256x256 GEMM ----------------
#define AS1C(p) (const __attribute__((address_space(1))) void*)(p)
#define AS3C(p) (__attribute__((address_space(3))) void*)(p)

// 1024 threads: one call covers 128 rows (row t>>3, 16B slot t&7), h picks half.
#define STAGE_A(arr, h, tile)                                                         \
    __builtin_amdgcn_global_load_lds(                                                 \
        AS1C(aStageBase + (size_t)((h) * 128) * K_DIM + (tile) * 64),                 \
        AS3C((char*)(arr) + (h) * 16384 + t * 16), 16, 0, 0)

#define STAGE_B(arr, h, tile)                                                         \
    __builtin_amdgcn_global_load_lds(                                                 \
        AS1C(bStageBase + (size_t)((h) * 128) * K_DIM + (tile) * 64),                 \
        AS3C((char*)(arr) + (h) * 16384 + t * 16), 16, 0, 0)

#define DSR(dst, addr, IMM) \
    asm volatile("ds_read_b128 %0, %1 offset:%c2" : "=v"(dst) : "v"(addr), "i"(IMM))

// one k-half: 4 A-frags (rows +mi*16 = imm mi*2048) + 4 B-frags (+ni*2048)
#define DSR8(aK, bK)            \
    DSR(a0, aK, 0);             \
    DSR(a1, aK, 2048);          \
    DSR(a2, aK, 4096);          \
    DSR(a3, aK, 6144);          \
    DSR(b0, bK, 0);             \
    DSR(b1, bK, 2048);          \
    DSR(b2, bK, 4096);          \
    DSR(b3, bK, 6144)

#define MM(AI, NI, AV, BV) \
    acc[AI][NI] = __builtin_amdgcn_mfma_f32_16x16x32_f16(AV, BV, acc[AI][NI], 0, 0, 0)

#define MFMA16()                                                      \
    MM(0, 0, a0, b0); MM(0, 1, a0, b1); MM(0, 2, a0, b2); MM(0, 3, a0, b3); \
    MM(1, 0, a1, b0); MM(1, 1, a1, b1); MM(1, 2, a1, b2); MM(1, 3, a1, b3); \
    MM(2, 0, a2, b0); MM(2, 1, a2, b1); MM(2, 2, a2, b2); MM(2, 3, a2, b3); \
    MM(3, 0, a3, b0); MM(3, 1, a3, b1); MM(3, 2, a3, b2); MM(3, 3, a3, b3)

#define BARR()  __builtin_amdgcn_s_barrier()
#define SB0()   __builtin_amdgcn_sched_barrier(0)
#define LGKM0() do { asm volatile("s_waitcnt lgkmcnt(0)" ::: "memory"); SB0(); } while (0)
#define VMC4()  asm volatile("s_waitcnt vmcnt(4)" ::: "memory")
#define PRIO1() __builtin_amdgcn_s_setprio(1)
#define PRIO0() __builtin_amdgcn_s_setprio(0)

// One K-tile (BK=64): prefetch 4 DMA for tile tl -> counted vmcnt -> 2 k-halves.
#define KTILE(aK0, aK1, bK0, bK1, Adst, Bdst, tl) do {                                \
    STAGE_A(Adst, 0, tl); STAGE_A(Adst, 1, tl);                                       \
    STAGE_B(Bdst, 0, tl); STAGE_B(Bdst, 1, tl);                                       \
    VMC4();                                 /* this tile's 4 DMA landed (mine) */     \
    BARR();                                 /* ... and everyone's */                  \
    DSR8(aK0, bK0);                                                                   \
    LGKM0(); PRIO1(); MFMA16(); PRIO0();                                              \
    DSR8(aK1, bK1);                                                                   \
    LGKM0(); PRIO1(); MFMA16(); PRIO0();                                              \
    BARR();                                 /* buffers free for next overwrite */     \
} while (0)

__global__ __launch_bounds__(1024, 4) void gemm_w16(const _Float16* __restrict__ Xh,
                                                    const _Float16* __restrict__ Wt,
                                                    const float* __restrict__ scale,
                                                    const float* __restrict__ bias,
                                                    float* __restrict__ C) {
    __shared__ __attribute__((aligned(128))) _Float16 As0_[16384];  // [256][64] f16
    __shared__ __attribute__((aligned(128))) _Float16 As1_[16384];
    __shared__ __attribute__((aligned(128))) _Float16 Bs0_[16384];
    __shared__ __attribute__((aligned(128))) _Float16 Bs1_[16384];

    // T1: XCD-aware bijective swizzle (512 blocks, 512 % 8 == 0)
    const int bid = blockIdx.x;
    const int swz = (bid & 7) * 64 + (bid >> 3);
    const int bm  = swz >> 4;            // 0..31
    const int bn  = swz & 15;            // 0..15

    const int t  = threadIdx.x;          // 0..1023
    const int l  = t & 63;
    const int w  = t >> 6;               // 16 waves: 4(M) x 4(N)
    const int wm = w >> 2, wn = w & 3;   // wave out: 64 rows x 64 cols
    const int lr = l & 15, lh = l >> 4;

    // staging: thread t covers rows (t>>3)+{0,128}, 16B k-slot t&7.
    // T2 rule-21: linear LDS dest; SOURCE k pre-XORed by ((row&7)<<4) bytes.
    const int rowIdx = t >> 3;           // 0..127
    const int kbSw   = ((t & 7) * 16) ^ ((rowIdx & 7) << 4);
    const _Float16* aStageBase = Xh + (size_t)(bm * 256 + rowIdx) * K_DIM + (kbSw >> 1);
    const _Float16* bStageBase = Wt + (size_t)(bn * 256 + rowIdx) * K_DIM + (kbSw >> 1);

    // ds_read addresses (r5/r7-verified pattern, 0 conflicts): row (w*64+lr),
    // byte-in-row ((lh*16)^(mask&48)) + k-half bit via m6 / 64^m6.
    const int  mask = (lr & 7) << 4;
    const uint32_t m6   = (uint32_t)(mask & 64);
    const uint32_t aoff = (uint32_t)((wm * 64 + lr) * 128 + ((lh * 16) ^ (mask & 48)));
    const uint32_t boff = (uint32_t)((wn * 64 + lr) * 128 + ((lh * 16) ^ (mask & 48)));
    const uint32_t aA0k0 = (uint32_t)(uintptr_t)As0_ + aoff + m6;
    const uint32_t aA0k1 = (uint32_t)(uintptr_t)As0_ + aoff + (64u ^ m6);
    const uint32_t aA1k0 = (uint32_t)(uintptr_t)As1_ + aoff + m6;
    const uint32_t aA1k1 = (uint32_t)(uintptr_t)As1_ + aoff + (64u ^ m6);
    const uint32_t bB0k0 = (uint32_t)(uintptr_t)Bs0_ + boff + m6;
    const uint32_t bB0k1 = (uint32_t)(uintptr_t)Bs0_ + boff + (64u ^ m6);
    const uint32_t bB1k0 = (uint32_t)(uintptr_t)Bs1_ + boff + m6;
    const uint32_t bB1k1 = (uint32_t)(uintptr_t)Bs1_ + boff + (64u ^ m6);

    f16x8 a0, a1, a2, a3, b0, b1, b2, b3;
    f32x4 acc[4][4] = {};

    // prologue: stage K-tile 0 into buf0 (4 DMA/thread outstanding)
    STAGE_A(As0_, 0, 0); STAGE_A(As0_, 1, 0);
    STAGE_B(Bs0_, 0, 0); STAGE_B(Bs0_, 1, 0);

#pragma unroll 1
    for (int i = 0; i < K_DIM / 128; ++i) {       // 32 iters, 2 K-tiles each
        const int t1 = 2 * i + 1;                 // <= 63
        const int t2 = (2 * i + 2) & 63;          // wraps only on last iter (data unused)
        KTILE(aA0k0, aA0k1, bB0k0, bB0k1, As1_, Bs1_, t1);   // tile 2i   (buf0)
        KTILE(aA1k0, aA1k1, bB1k0, bB1k1, As0_, Bs0_, t2);   // tile 2i+1 (buf1)
    }
    asm volatile("s_waitcnt vmcnt(0)" ::: "memory");  // drain dangling prefetch

    // epilogue: C/D layout col = lane&15, row = (lane>>4)*4 + reg  [m89-verified]
    const int col0 = bn * 256 + wn * 64 + lr;
    const int row0 = bm * 256 + wm * 64 + lh * 4;
    float sc[4], bi[4];
#pragma unroll
    for (int ni = 0; ni < 4; ++ni) {
        sc[ni] = scale[col0 + ni * 16];
        bi[ni] = bias[col0 + ni * 16];
    }
#pragma unroll
    for (int mi = 0; mi < 4; ++mi)
#pragma unroll
        for (int r = 0; r < 4; ++r) {
            const size_t rowOff = (size_t)(row0 + mi * 16 + r) * N_DIM;
#pragma unroll
            for (int ni = 0; ni < 4; ++ni)
                C[rowOff + col0 + ni * 16] = acc[mi][ni][r] * sc[ni] + bi[ni];
        }
}

extern "C" void kernel_launch(void* const* d_in, const int* in_sizes, int n_in,
                              void* d_out, int out_size, void* d_ws, size_t ws_size,
                              hipStream_t stream) {
    const float* x     = (const float*)d_in[0];
    const int*   wq    = (const int*)d_in[1];
    const float* scale = (const float*)d_in[2];
    const float* bias  = (const float*)d_in[3];
    float* out = (float*)d_out;

    const size_t needW = (size_t)N_DIM * K_DIM * sizeof(_Float16);   // 33.5 MB
    _Float16* Wt = (_Float16*)d_ws;
    _Float16* Xh = (_Float16*)((char*)d_ws + needW);                 // ws >= 100.7MB (r4)

    dim3 tgrid(N_DIM / 64, K_DIM / 64);
    dequant_w_to_f16<<<tgrid, 256, 0, stream>>>(wq, Wt);
    convert_x_to_f16<<<((size_t)M_DIM * K_DIM) / (256 * 8), 256, 0, stream>>>(x, Xh);

    const int nblocks = (M_DIM / 256) * (N_DIM / 256);               // 512
    gemm_w16<<<nblocks, 1024, 0, stream>>>(Xh, Wt, scale, bias, out);
}

// Round 10
// 287.614 us; speedup vs baseline: 1.0400x; 1.0113x over previous
//
#include <hip/hip_runtime.h>
#include <stdint.h>

// EETQLinear w8a16: out[m,n] = (sum_k x[m,k]*wq[k,n]) * scale[n] + bias[n]
// M=8192, K=4096, N=4096. Dtypes (r3/r4-verified): x/scale/bias/out f32, wq int32.
// v10: BK=32, 4-deep LDS buffer rotation, ONE barrier per K-tile, vmcnt(12)
//      (3-tile DMA lead -> landed-wait ~0), waves free to drift a full tile so
//      MFMA of one wave overlaps ds_reads of another. 256x256 tile, 8 waves
//      (2Mx4N, 128x64 out). Swizzle re-derived for 64B rows: slot ^= (row>>1)&3
//      both sides (conflict-free: 2 lanes/16B-slot per 16-lane phase).

typedef __attribute__((ext_vector_type(4))) float     f32x4;
typedef __attribute__((ext_vector_type(8))) _Float16  f16x8;

#define M_DIM 8192
#define N_DIM 4096
#define K_DIM 4096

// ---------------- prologue kernels (r4-verified) ----------------
__global__ __launch_bounds__(256) void convert_x_to_f16(const float* __restrict__ x,
                                                        _Float16* __restrict__ Xh) {
    const size_t i = ((size_t)blockIdx.x * 256 + threadIdx.x) * 8;
    float4 v0 = *(const float4*)(x + i);
    float4 v1 = *(const float4*)(x + i + 4);
    f16x8 h;
    h[0] = (_Float16)v0.x; h[1] = (_Float16)v0.y; h[2] = (_Float16)v0.z; h[3] = (_Float16)v0.w;
    h[4] = (_Float16)v1.x; h[5] = (_Float16)v1.y; h[6] = (_Float16)v1.z; h[7] = (_Float16)v1.w;
    *(f16x8*)(Xh + i) = h;
}

__global__ __launch_bounds__(256) void dequant_w_to_f16(const int* __restrict__ wq,
                                                        _Float16* __restrict__ Wt) {
    __shared__ _Float16 tile[64][65];
    const int n0 = blockIdx.x * 64;
    const int k0 = blockIdx.y * 64;
    const int t  = threadIdx.x;
    const int r  = t >> 2;
    const int c0 = (t & 3) * 16;
    const int* src = wq + (size_t)(k0 + r) * N_DIM + n0 + c0;
#pragma unroll
    for (int j = 0; j < 4; ++j) {
        int4 q = *(const int4*)(src + j * 4);
        tile[c0 + j * 4 + 0][r] = (_Float16)q.x;
        tile[c0 + j * 4 + 1][r] = (_Float16)q.y;
        tile[c0 + j * 4 + 2][r] = (_Float16)q.z;
        tile[c0 + j * 4 + 3][r] = (_Float16)q.w;
    }
    __syncthreads();
    const int nn  = t >> 2;
    const int cc0 = (t & 3) * 16;
    _Float16 vals[16] __attribute__((aligned(16)));
#pragma unroll
    for (int j = 0; j < 16; ++j) vals[j] = tile[nn][cc0 + j];
    _Float16* dst = Wt + (size_t)(n0 + nn) * K_DIM + k0 + cc0;
    *(float4*)(dst + 0) = *(const float4*)(vals + 0);
    *(float4*)(dst + 8) = *(const float4*)(vals + 8);
}

// ---------------- 4-buffer BK=32 GEMM ----------------
#define AS1C(p) (const __attribute__((address_space(1))) void*)(p)
#define AS3C(p) (__attribute__((address_space(3))) void*)(p)

// stage tile `tl` into buffer byte-offset BB (static): A halves then B halves.
// thread t: row t>>2 (+128 for h=1), 16B slot t&3 (source pre-XOR-swizzled).
#define STAGE_TILE(BB, tl) do {                                                       \
    __builtin_amdgcn_global_load_lds(AS1C(aStageBase + (size_t)(tl) * 32),            \
        AS3C(ldsBase + (BB) + t * 16), 16, 0, 0);                                     \
    __builtin_amdgcn_global_load_lds(AS1C(aStageBase + aHalfJump + (size_t)(tl) * 32),\
        AS3C(ldsBase + (BB) + 8192 + t * 16), 16, 0, 0);                              \
    __builtin_amdgcn_global_load_lds(AS1C(bStageBase + (size_t)(tl) * 32),            \
        AS3C(ldsBase + (BB) + 16384 + t * 16), 16, 0, 0);                             \
    __builtin_amdgcn_global_load_lds(AS1C(bStageBase + bHalfJump + (size_t)(tl) * 32),\
        AS3C(ldsBase + (BB) + 24576 + t * 16), 16, 0, 0);                             \
} while (0)

#define DSR(dst, addr, IMM) \
    asm volatile("ds_read_b128 %0, %1 offset:%c2" : "=v"(dst) : "v"(addr), "i"(IMM))

// all 12 reads of buffer b (static): AR = aLo (b<2) or aHi (b>=2), IB = (b&1)*32768
#define READS(AR, IB)                                        \
    DSR(a0, AR, (IB) + 0 * 1024);                            \
    DSR(a1, AR, (IB) + 1 * 1024);                            \
    DSR(a2, AR, (IB) + 2 * 1024);                            \
    DSR(a3, AR, (IB) + 3 * 1024);                            \
    DSR(a4, AR, (IB) + 4 * 1024);                            \
    DSR(a5, AR, (IB) + 5 * 1024);                            \
    DSR(a6, AR, (IB) + 6 * 1024);                            \
    DSR(a7, AR, (IB) + 7 * 1024);                            \
    DSR(b0, AR, (IB) + 16384 + 0 * 1024);                    \
    DSR(b1, AR, (IB) + 16384 + 1 * 1024);                    \
    DSR(b2, AR, (IB) + 16384 + 2 * 1024);                    \
    DSR(b3, AR, (IB) + 16384 + 3 * 1024)

#define MM(AI, NI, AV, BV) \
    acc[AI][NI] = __builtin_amdgcn_mfma_f32_16x16x32_f16(AV, BV, acc[AI][NI], 0, 0, 0)

#define MFMA32()                                                          \
    MM(0, 0, a0, b0); MM(0, 1, a0, b1); MM(0, 2, a0, b2); MM(0, 3, a0, b3); \
    MM(1, 0, a1, b0); MM(1, 1, a1, b1); MM(1, 2, a1, b2); MM(1, 3, a1, b3); \
    MM(2, 0, a2, b0); MM(2, 1, a2, b1); MM(2, 2, a2, b2); MM(2, 3, a2, b3); \
    MM(3, 0, a3, b0); MM(3, 1, a3, b1); MM(3, 2, a3, b2); MM(3, 3, a3, b3); \
    MM(4, 0, a4, b0); MM(4, 1, a4, b1); MM(4, 2, a4, b2); MM(4, 3, a4, b3); \
    MM(5, 0, a5, b0); MM(5, 1, a5, b1); MM(5, 2, a5, b2); MM(5, 3, a5, b3); \
    MM(6, 0, a6, b0); MM(6, 1, a6, b1); MM(6, 2, a6, b2); MM(6, 3, a6, b3); \
    MM(7, 0, a7, b0); MM(7, 1, a7, b1); MM(7, 2, a7, b2); MM(7, 3, a7, b3)

#define BARR()  __builtin_amdgcn_s_barrier()
#define SB0()   __builtin_amdgcn_sched_barrier(0)
#define LGKM0() do { asm volatile("s_waitcnt lgkmcnt(0)" ::: "memory"); SB0(); } while (0)
#define VMC12() asm volatile("s_waitcnt vmcnt(12)" ::: "memory")
#define PRIO1() __builtin_amdgcn_s_setprio(1)
#define PRIO0() __builtin_amdgcn_s_setprio(0)

// One K-tile slot j (static 0..3): stage tile base+j+3 into buf (j+3)&3, confirm
// tile base+j landed (vmcnt: 12 newer loads = 3 in-flight tiles), ONE barrier,
// 12 reads, lgkm0, 32 MFMA. Buffer overwritten is tile (base+j-1)'s, whose reads
// completed before each wave's BARR (lgkm0 precedes it) -> race-free.
#define KSLOT(j, AR) do {                                                             \
    const int tl = (base + (j) + 3) & 127;                                            \
    STAGE_TILE((((j) + 3) & 3) * 32768, tl);                                          \
    VMC12(); BARR();                                                                  \
    READS(AR, ((j) & 1) * 32768);                                                     \
    LGKM0(); PRIO1(); MFMA32(); PRIO0();                                              \
} while (0)

__global__ __launch_bounds__(512, 2) void gemm_d4(const _Float16* __restrict__ Xh,
                                                  const _Float16* __restrict__ Wt,
                                                  const float* __restrict__ scale,
                                                  const float* __restrict__ bias,
                                                  float* __restrict__ C) {
    // 4 rotating buffers, 32KB each: [A 16KB | B 16KB], rows of 64B (BK=32)
    __shared__ __attribute__((aligned(128))) _Float16 L[65536];   // 128 KB
    char* ldsBase = (char*)L;

    // T1: XCD-aware bijective swizzle (512 blocks, 512 % 8 == 0)
    const int bid = blockIdx.x;
    const int swz = (bid & 7) * 64 + (bid >> 3);
    const int bm  = swz >> 4;            // 0..31
    const int bn  = swz & 15;            // 0..15

    const int t  = threadIdx.x;          // 0..511
    const int l  = t & 63;
    const int w  = t >> 6;               // 8 waves: 2(M) x 4(N)
    const int wm = w >> 2, wn = w & 3;   // wave out: 128 rows x 64 cols
    const int lr = l & 15, lh = l >> 4;

    // staging: thread t covers row t>>2 (+128 for h=1), slot t&3.
    // Source slot pre-XORed by ((row>>1)&3) (involution; h=+128 preserves it).
    const int rowIdx = t >> 2;                         // 0..127
    const int kbSw   = ((t & 3) ^ ((rowIdx >> 1) & 3)) * 16;   // bytes
    const _Float16* aStageBase = Xh + (size_t)(bm * 256 + rowIdx) * K_DIM + (kbSw >> 1);
    const _Float16* bStageBase = Wt + (size_t)(bn * 256 + rowIdx) * K_DIM + (kbSw >> 1);
    const size_t aHalfJump = (size_t)128 * K_DIM;
    const size_t bHalfJump = (size_t)128 * K_DIM;

    // ds_read lane addresses: row*64 + ((lh ^ ((row>>1)&3))<<4); frag i at +i*1024.
    // (row>>1)&3 == (lr>>1)&3 for all frags (row = W + lr, W multiple of 16).
    const uint32_t xr   = (uint32_t)((lh ^ ((lr >> 1) & 3)) << 4);
    const uint32_t aoff = (uint32_t)((wm * 128 + lr) * 64) + xr;
    const uint32_t boff = (uint32_t)((wn * 64 + lr) * 64) + xr;  // + 16384 via imm
    const uint32_t aLo  = (uint32_t)(uintptr_t)L + aoff;           // buffers 0,1
    const uint32_t aHi  = (uint32_t)(uintptr_t)L + 65536 + aoff;   // buffers 2,3
    const uint32_t bLo  = (uint32_t)(uintptr_t)L + boff;
    const uint32_t bHi  = (uint32_t)(uintptr_t)L + 65536 + boff;

    f16x8 a0, a1, a2, a3, a4, a5, a6, a7, b0, b1, b2, b3;
    f32x4 acc[8][4] = {};

    // prologue: stage tiles 0,1,2 into buffers 0,1,2 (12 DMA outstanding)
    STAGE_TILE(0 * 32768, 0);
    STAGE_TILE(1 * 32768, 1);
    STAGE_TILE(2 * 32768, 2);

#pragma unroll 1
    for (int it = 0; it < 32; ++it) {             // 128 K-tiles, 4 per iteration
        const int base = it * 4;
        // A-reads use aLo/aHi; B folded via +16384 imm, but B needs its own lane
        // offset -> READS uses one addr reg per buffer pair with A at +0,B at +16384:
        // aoff/boff differ, so issue A from aLo/aHi and B from bLo/bHi:
        {   const int tl = (base + 3) & 127;
            STAGE_TILE(3 * 32768, tl);
            VMC12(); BARR();
            DSR(a0, aLo, 0);     DSR(a1, aLo, 1024);  DSR(a2, aLo, 2048);
            DSR(a3, aLo, 3072);  DSR(a4, aLo, 4096);  DSR(a5, aLo, 5120);
            DSR(a6, aLo, 6144);  DSR(a7, aLo, 7168);
            DSR(b0, bLo, 16384); DSR(b1, bLo, 17408); DSR(b2, bLo, 18432);
            DSR(b3, bLo, 19456);
            LGKM0(); PRIO1(); MFMA32(); PRIO0();
        }
        {   const int tl = (base + 4) & 127;
            STAGE_TILE(0 * 32768, tl);
            VMC12(); BARR();
            DSR(a0, aLo, 32768 + 0);    DSR(a1, aLo, 32768 + 1024);
            DSR(a2, aLo, 32768 + 2048); DSR(a3, aLo, 32768 + 3072);
            DSR(a4, aLo, 32768 + 4096); DSR(a5, aLo, 32768 + 5120);
            DSR(a6, aLo, 32768 + 6144); DSR(a7, aLo, 32768 + 7168);
            DSR(b0, bLo, 49152);        DSR(b1, bLo, 50176);
            DSR(b2, bLo, 51200);        DSR(b3, bLo, 52224);
            LGKM0(); PRIO1(); MFMA32(); PRIO0();
        }
        {   const int tl = (base + 5) & 127;
            STAGE_TILE(1 * 32768, tl);
            VMC12(); BARR();
            DSR(a0, aHi, 0);     DSR(a1, aHi, 1024);  DSR(a2, aHi, 2048);
            DSR(a3, aHi, 3072);  DSR(a4, aHi, 4096);  DSR(a5, aHi, 5120);
            DSR(a6, aHi, 6144);  DSR(a7, aHi, 7168);
            DSR(b0, bHi, 16384); DSR(b1, bHi, 17408); DSR(b2, bHi, 18432);
            DSR(b3, bHi, 19456);
            LGKM0(); PRIO1(); MFMA32(); PRIO0();
        }
        {   const int tl = (base + 6) & 127;
            STAGE_TILE(2 * 32768, tl);
            VMC12(); BARR();
            DSR(a0, aHi, 32768 + 0);    DSR(a1, aHi, 32768 + 1024);
            DSR(a2, aHi, 32768 + 2048); DSR(a3, aHi, 32768 + 3072);
            DSR(a4, aHi, 32768 + 4096); DSR(a5, aHi, 32768 + 5120);
            DSR(a6, aHi, 32768 + 6144); DSR(a7, aHi, 32768 + 7168);
            DSR(b0, bHi, 49152);        DSR(b1, bHi, 50176);
            DSR(b2, bHi, 51200);        DSR(b3, bHi, 52224);
            LGKM0(); PRIO1(); MFMA32(); PRIO0();
        }
    }
    asm volatile("s_waitcnt vmcnt(0)" ::: "memory");  // drain dangling prefetches

    // epilogue: C/D layout col = lane&15, row = (lane>>4)*4 + reg  [m89-verified]
    const int col0 = bn * 256 + wn * 64 + lr;
    const int row0 = bm * 256 + wm * 128 + lh * 4;
    float sc[4], bi[4];
#pragma unroll
    for (int ni = 0; ni < 4; ++ni) {
        sc[ni] = scale[col0 + ni * 16];
        bi[ni] = bias[col0 + ni * 16];
    }
#pragma unroll
    for (int ai = 0; ai < 8; ++ai)
#pragma unroll
        for (int r = 0; r < 4; ++r) {
            const size_t rowOff = (size_t)(row0 + ai * 16 + r) * N_DIM;
#pragma unroll
            for (int ni = 0; ni < 4; ++ni)
                C[rowOff + col0 + ni * 16] = acc[ai][ni][r] * sc[ni] + bi[ni];
        }
}

extern "C" void kernel_launch(void* const* d_in, const int* in_sizes, int n_in,
                              void* d_out, int out_size, void* d_ws, size_t ws_size,
                              hipStream_t stream) {
    const float* x     = (const float*)d_in[0];
    const int*   wq    = (const int*)d_in[1];
    const float* scale = (const float*)d_in[2];
    const float* bias  = (const float*)d_in[3];
    float* out = (float*)d_out;

    const size_t needW = (size_t)N_DIM * K_DIM * sizeof(_Float16);   // 33.5 MB
    _Float16* Wt = (_Float16*)d_ws;
    _Float16* Xh = (_Float16*)((char*)d_ws + needW);                 // ws >= 100.7MB (r4)

    dim3 tgrid(N_DIM / 64, K_DIM / 64);
    dequant_w_to_f16<<<tgrid, 256, 0, stream>>>(wq, Wt);
    convert_x_to_f16<<<((size_t)M_DIM * K_DIM) / (256 * 8), 256, 0, stream>>>(x, Xh);

    const int nblocks = (M_DIM / 256) * (N_DIM / 256);               // 512
    gemm_d4<<<nblocks, 512, 0, stream>>>(Xh, Wt, scale, bias, out);
}